// Round 1
// baseline (946.652 us; speedup 1.0000x reference)
//
#include <hip/hip_runtime.h>
#include <hip/hip_bf16.h>

#define IN_DIM  128
#define OUT_DIM 64

// ---------------------------------------------------------------------------
// Degree / normalization
// ---------------------------------------------------------------------------
__global__ void k_init_deg(float* __restrict__ deg, int n) {
    int i = blockIdx.x * blockDim.x + threadIdx.x;
    if (i < n) deg[i] = 1.0f;   // self-loop contributes 1 to in-degree
}

__global__ void k_count_deg(const int* __restrict__ dst, float* __restrict__ deg, int nE) {
    int e = blockIdx.x * blockDim.x + threadIdx.x;
    if (e < nE) unsafeAtomicAdd(&deg[dst[e]], 1.0f);   // exact for counts < 2^24
}

__global__ void k_rsqrt(float* __restrict__ deg, int n) {
    int i = blockIdx.x * blockDim.x + threadIdx.x;
    if (i < n) deg[i] = rsqrtf(deg[i]);
}

// ---------------------------------------------------------------------------
// Layer 1 linear: hs[i] = dinv[i] * (x[i] @ W1);  agg[i] initialized to hs[i]
// (self-loop term folded in: out1[i] = dinv[i]*(sum_{j->i} hs[j] + hs[i]))
// ---------------------------------------------------------------------------
__global__ __launch_bounds__(256) void k_lin1(const float* __restrict__ x,
                                              const float* __restrict__ W,
                                              const float* __restrict__ dinv,
                                              float* __restrict__ hs,
                                              float* __restrict__ agg, int n) {
    __shared__ float Wl[IN_DIM * OUT_DIM];   // 32 KiB
    for (int i = threadIdx.x; i < IN_DIM * OUT_DIM; i += 256) Wl[i] = W[i];
    __syncthreads();
    int wid = threadIdx.x >> 6, lane = threadIdx.x & 63;
    for (int row = blockIdx.x * 4 + wid; row < n; row += gridDim.x * 4) {
        const float4* xp = (const float4*)(x + (size_t)row * IN_DIM);
        float acc = 0.f;
#pragma unroll
        for (int k4 = 0; k4 < IN_DIM / 4; ++k4) {
            float4 xv = xp[k4];                       // wave-uniform broadcast load
            acc += xv.x * Wl[(4 * k4 + 0) * 64 + lane];
            acc += xv.y * Wl[(4 * k4 + 1) * 64 + lane];
            acc += xv.z * Wl[(4 * k4 + 2) * 64 + lane];
            acc += xv.w * Wl[(4 * k4 + 3) * 64 + lane];
        }
        float v = dinv[row] * acc;
        size_t o = (size_t)row * 64 + lane;
        hs[o] = v;
        agg[o] = v;
    }
}

// ---------------------------------------------------------------------------
// Layer 2 linear, fused with relu(dinv * agg1) on the input:
//   h1[i]  = relu(dinv[i] * agg1[i])
//   hs2[i] = dinv[i] * (h1[i] @ W2);  out initialized to hs2 (self-loop term)
// ---------------------------------------------------------------------------
__global__ __launch_bounds__(256) void k_lin2(const float* __restrict__ agg1,
                                              const float* __restrict__ W,
                                              const float* __restrict__ dinv,
                                              float* __restrict__ hs2,
                                              float* __restrict__ out, int n) {
    __shared__ float Wl[OUT_DIM * OUT_DIM];  // 16 KiB
    for (int i = threadIdx.x; i < OUT_DIM * OUT_DIM; i += 256) Wl[i] = W[i];
    __syncthreads();
    int wid = threadIdx.x >> 6, lane = threadIdx.x & 63;
    for (int row = blockIdx.x * 4 + wid; row < n; row += gridDim.x * 4) {
        const float4* xp = (const float4*)(agg1 + (size_t)row * OUT_DIM);
        float dv = dinv[row];
        float acc = 0.f;
#pragma unroll
        for (int k4 = 0; k4 < OUT_DIM / 4; ++k4) {
            float4 xv = xp[k4];                       // wave-uniform broadcast load
            float a = fmaxf(dv * xv.x, 0.f);
            float b = fmaxf(dv * xv.y, 0.f);
            float c = fmaxf(dv * xv.z, 0.f);
            float d = fmaxf(dv * xv.w, 0.f);
            acc += a * Wl[(4 * k4 + 0) * 64 + lane];
            acc += b * Wl[(4 * k4 + 1) * 64 + lane];
            acc += c * Wl[(4 * k4 + 2) * 64 + lane];
            acc += d * Wl[(4 * k4 + 3) * 64 + lane];
        }
        float v = dv * acc;
        size_t o = (size_t)row * 64 + lane;
        hs2[o] = v;
        out[o] = v;
    }
}

// ---------------------------------------------------------------------------
// Edge aggregation: one wave per edge (lane = feature dim).
//   agg[dst][lane] += hs[src][lane]
// ---------------------------------------------------------------------------
__global__ __launch_bounds__(256) void k_edge(const float* __restrict__ hs,
                                              const int* __restrict__ src,
                                              const int* __restrict__ dst,
                                              float* __restrict__ agg, int nE) {
    int lane = threadIdx.x & 63;
    int w = (blockIdx.x * blockDim.x + threadIdx.x) >> 6;
    int nw = (gridDim.x * blockDim.x) >> 6;
    for (int e = w; e < nE; e += nw) {
        int s = src[e];                               // wave-uniform
        int d = dst[e];
        float v = hs[(size_t)s * 64 + lane];          // 256B coalesced gather
        unsafeAtomicAdd(&agg[(size_t)d * 64 + lane], v);
    }
}

// ---------------------------------------------------------------------------
// Final per-node scale: out[i][:] *= dinv[i]
// ---------------------------------------------------------------------------
__global__ void k_scale(float* __restrict__ out, const float* __restrict__ dinv, int n64) {
    int i = blockIdx.x * blockDim.x + threadIdx.x;
    if (i < n64) out[i] *= dinv[i >> 6];
}

// ---------------------------------------------------------------------------
extern "C" void kernel_launch(void* const* d_in, const int* in_sizes, int n_in,
                              void* d_out, int out_size, void* d_ws, size_t ws_size,
                              hipStream_t stream) {
    const float* x  = (const float*)d_in[0];
    const int*   ei = (const int*)d_in[1];
    const float* W1 = (const float*)d_in[2];
    const float* W2 = (const float*)d_in[3];
    float* out = (float*)d_out;

    int n  = in_sizes[0] / IN_DIM;   // 100000
    int nE = in_sizes[1] / 2;        // 1600000
    const int* src = ei;             // edge_index[0]
    const int* dst = ei + nE;        // edge_index[1]

    float* ws = (float*)d_ws;
    float* dinv = ws;                                    // n floats
    size_t off = ((size_t)n + 255) & ~(size_t)255;       // align
    float* hs  = ws + off;                               // n*64 floats (layer1 hs, then layer2 hs2)
    float* agg = hs + (size_t)n * 64;                    // n*64 floats (layer1 accumulator)

    // normalization
    k_init_deg<<<(n + 255) / 256, 256, 0, stream>>>(dinv, n);
    k_count_deg<<<(nE + 255) / 256, 256, 0, stream>>>(dst, dinv, nE);
    k_rsqrt<<<(n + 255) / 256, 256, 0, stream>>>(dinv, n);

    // layer 1
    k_lin1<<<1024, 256, 0, stream>>>(x, W1, dinv, hs, agg, n);
    k_edge<<<8192, 256, 0, stream>>>(hs, src, dst, agg, nE);

    // layer 2 (reuses hs buffer for hs2; d_out is the accumulator)
    k_lin2<<<1024, 256, 0, stream>>>(agg, W2, dinv, hs, out, n);
    k_edge<<<8192, 256, 0, stream>>>(hs, src, dst, out, nE);

    // final dinv[dst] scaling
    k_scale<<<(n * 64 + 255) / 256, 256, 0, stream>>>(out, dinv, n * 64);
}

// Round 2
// 584.180 us; speedup vs baseline: 1.6205x; 1.6205x over previous
//
#include <hip/hip_runtime.h>
#include <hip/hip_bf16.h>

#define IN_DIM  128
#define OUT_DIM 64
#define SCAN_CHUNK 1024   // 256 threads x 4 elems

// ---------------------------------------------------------------------------
// CSR build: histogram -> exclusive scan -> scatter edges by dst
// ---------------------------------------------------------------------------
__global__ void k_zero(unsigned* __restrict__ p, int n) {
    int i = blockIdx.x * blockDim.x + threadIdx.x;
    if (i < n) p[i] = 0u;
}

__global__ void k_hist(const int* __restrict__ dst, unsigned* __restrict__ cnt, int nE) {
    int e = blockIdx.x * blockDim.x + threadIdx.x;
    if (e < nE) atomicAdd(&cnt[dst[e]], 1u);
}

// Per-block scan of 1024 counts; also emits dinv = rsqrt(deg) (deg = cnt+1 self-loop)
__global__ __launch_bounds__(256) void k_scanA(const unsigned* __restrict__ cnt,
                                               unsigned* __restrict__ offs,
                                               unsigned* __restrict__ partials,
                                               float* __restrict__ dinv, int n) {
    __shared__ unsigned sums[256];
    int base = blockIdx.x * SCAN_CHUNK + threadIdx.x * 4;
    unsigned v[4]; unsigned s = 0;
#pragma unroll
    for (int k = 0; k < 4; ++k) {
        int i = base + k;
        unsigned c = (i < n) ? cnt[i] : 0u;
        if (i < n) dinv[i] = rsqrtf((float)c + 1.0f);
        v[k] = s; s += c;
    }
    sums[threadIdx.x] = s;
    __syncthreads();
    for (int d = 1; d < 256; d <<= 1) {
        unsigned t = (threadIdx.x >= (unsigned)d) ? sums[threadIdx.x - d] : 0u;
        __syncthreads();
        sums[threadIdx.x] += t;
        __syncthreads();
    }
    unsigned excl = sums[threadIdx.x] - s;
#pragma unroll
    for (int k = 0; k < 4; ++k) {
        int i = base + k;
        if (i < n) offs[i] = excl + v[k];
    }
    if (threadIdx.x == 255) partials[blockIdx.x] = sums[255];
}

// Exclusive scan of block partials (nb <= 256 for n <= 262144)
__global__ void k_scanB(unsigned* __restrict__ partials, int nb) {
    __shared__ unsigned s[256];
    unsigned v = (threadIdx.x < (unsigned)nb) ? partials[threadIdx.x] : 0u;
    s[threadIdx.x] = v;
    __syncthreads();
    for (int d = 1; d < 256; d <<= 1) {
        unsigned t = (threadIdx.x >= (unsigned)d) ? s[threadIdx.x - d] : 0u;
        __syncthreads();
        s[threadIdx.x] += t;
        __syncthreads();
    }
    if (threadIdx.x < (unsigned)nb) partials[threadIdx.x] = s[threadIdx.x] - v;
}

// Add block offsets; init cursor = row start (scatter turns it into row end)
__global__ void k_scanC(unsigned* __restrict__ offs, const unsigned* __restrict__ partials,
                        unsigned* __restrict__ curs, int n) {
    int i = blockIdx.x * blockDim.x + threadIdx.x;
    if (i < n) {
        unsigned o = offs[i] + partials[i / SCAN_CHUNK];
        offs[i] = o;
        curs[i] = o;
    }
}

__global__ void k_scatter(const int* __restrict__ src, const int* __restrict__ dst,
                          unsigned* __restrict__ curs, int* __restrict__ perm, int nE) {
    int e = blockIdx.x * blockDim.x + threadIdx.x;
    if (e < nE) {
        unsigned p = atomicAdd(&curs[dst[e]], 1u);
        perm[p] = src[e];
    }
}

// ---------------------------------------------------------------------------
// Layer 1 linear: hs[i] = dinv[i] * (x[i] @ W1)
// ---------------------------------------------------------------------------
__global__ __launch_bounds__(256) void k_lin1(const float* __restrict__ x,
                                              const float* __restrict__ W,
                                              const float* __restrict__ dinv,
                                              float* __restrict__ hs, int n) {
    __shared__ float Wl[IN_DIM * OUT_DIM];   // 32 KiB
    for (int i = threadIdx.x; i < IN_DIM * OUT_DIM; i += 256) Wl[i] = W[i];
    __syncthreads();
    int wid = threadIdx.x >> 6, lane = threadIdx.x & 63;
    for (int row = blockIdx.x * 4 + wid; row < n; row += gridDim.x * 4) {
        const float4* xp = (const float4*)(x + (size_t)row * IN_DIM);
        float acc = 0.f;
#pragma unroll
        for (int k4 = 0; k4 < IN_DIM / 4; ++k4) {
            float4 xv = xp[k4];
            acc += xv.x * Wl[(4 * k4 + 0) * 64 + lane];
            acc += xv.y * Wl[(4 * k4 + 1) * 64 + lane];
            acc += xv.z * Wl[(4 * k4 + 2) * 64 + lane];
            acc += xv.w * Wl[(4 * k4 + 3) * 64 + lane];
        }
        hs[(size_t)row * 64 + lane] = dinv[row] * acc;
    }
}

// ---------------------------------------------------------------------------
// Layer 2 linear fused with relu(dinv*agg1): hs2[i] = dinv[i]*(relu(dinv[i]*agg1[i]) @ W2)
// ---------------------------------------------------------------------------
__global__ __launch_bounds__(256) void k_lin2(const float* __restrict__ agg1,
                                              const float* __restrict__ W,
                                              const float* __restrict__ dinv,
                                              float* __restrict__ hs2, int n) {
    __shared__ float Wl[OUT_DIM * OUT_DIM];  // 16 KiB
    for (int i = threadIdx.x; i < OUT_DIM * OUT_DIM; i += 256) Wl[i] = W[i];
    __syncthreads();
    int wid = threadIdx.x >> 6, lane = threadIdx.x & 63;
    for (int row = blockIdx.x * 4 + wid; row < n; row += gridDim.x * 4) {
        const float4* xp = (const float4*)(agg1 + (size_t)row * OUT_DIM);
        float dv = dinv[row];
        float acc = 0.f;
#pragma unroll
        for (int k4 = 0; k4 < OUT_DIM / 4; ++k4) {
            float4 xv = xp[k4];
            float a = fmaxf(dv * xv.x, 0.f);
            float b = fmaxf(dv * xv.y, 0.f);
            float c = fmaxf(dv * xv.z, 0.f);
            float d = fmaxf(dv * xv.w, 0.f);
            acc += a * Wl[(4 * k4 + 0) * 64 + lane];
            acc += b * Wl[(4 * k4 + 1) * 64 + lane];
            acc += c * Wl[(4 * k4 + 2) * 64 + lane];
            acc += d * Wl[(4 * k4 + 3) * 64 + lane];
        }
        hs2[(size_t)row * 64 + lane] = dv * acc;
    }
}

// ---------------------------------------------------------------------------
// CSR gather: one wave per node. acc = hs[r] (self-loop) + sum over neighbors.
// FIN: apply final dinv[r] scaling (layer-2 output).
// ---------------------------------------------------------------------------
template <bool FIN>
__global__ __launch_bounds__(256) void k_gather(const float* __restrict__ hs,
                                                const unsigned* __restrict__ offs,
                                                const unsigned* __restrict__ ends,
                                                const int* __restrict__ perm,
                                                const float* __restrict__ dinv,
                                                float* __restrict__ outb, int n) {
    int lane = threadIdx.x & 63;
    int r = blockIdx.x * 4 + (threadIdx.x >> 6);
    if (r >= n) return;
    unsigned beg = offs[r], end = ends[r];
    float acc = hs[(size_t)r * 64 + lane];          // self-loop term
    for (unsigned e0 = beg; e0 < end; e0 += 64) {
        unsigned c = min(64u, end - e0);
        int sl = (lane < (int)c) ? perm[e0 + lane] : 0;   // coalesced edge-list read
        for (unsigned k = 0; k < c; ++k) {
            int s = __shfl(sl, (int)k);                   // broadcast src id
            acc += hs[(size_t)s * 64 + lane];             // 256B coalesced gather
        }
    }
    if (FIN) acc *= dinv[r];
    outb[(size_t)r * 64 + lane] = acc;
}

// ---------------------------------------------------------------------------
extern "C" void kernel_launch(void* const* d_in, const int* in_sizes, int n_in,
                              void* d_out, int out_size, void* d_ws, size_t ws_size,
                              hipStream_t stream) {
    const float* x  = (const float*)d_in[0];
    const int*   ei = (const int*)d_in[1];
    const float* W1 = (const float*)d_in[2];
    const float* W2 = (const float*)d_in[3];
    float* out = (float*)d_out;

    int n  = in_sizes[0] / IN_DIM;   // 100000
    int nE = in_sizes[1] / 2;        // 1600000
    const int* src = ei;
    const int* dst = ei + nE;

    // workspace carve-up (all 256B-aligned)
    char* w = (char*)d_ws;
    size_t nAl = ((size_t)n * 4 + 255) & ~(size_t)255;
    float*    dinv     = (float*)w;                 w += nAl;
    unsigned* cnt      = (unsigned*)w;              w += nAl;
    unsigned* offs     = (unsigned*)w;              w += nAl;
    unsigned* curs     = (unsigned*)w;              w += nAl;
    unsigned* partials = (unsigned*)w;              w += 4096;
    int*      perm     = (int*)w;                   w += ((size_t)nE * 4 + 255) & ~(size_t)255;
    float*    hs       = (float*)w;                 w += (size_t)n * 64 * 4;
    float*    agg      = (float*)w;

    int nb   = (n + SCAN_CHUNK - 1) / SCAN_CHUNK;   // 98 blocks of scan
    int gE   = (nE + 255) / 256;
    int gN   = (n + 255) / 256;
    int gRow = (n + 3) / 4;                          // 1 wave per node

    // --- CSR build ---
    k_zero<<<gN, 256, 0, stream>>>(cnt, n);
    k_hist<<<gE, 256, 0, stream>>>(dst, cnt, nE);
    k_scanA<<<nb, 256, 0, stream>>>(cnt, offs, partials, dinv, n);
    k_scanB<<<1, 256, 0, stream>>>(partials, nb);
    k_scanC<<<gN, 256, 0, stream>>>(offs, partials, curs, n);
    k_scatter<<<gE, 256, 0, stream>>>(src, dst, curs, perm, nE);
    // after k_scatter: curs[r] == row end

    // --- layer 1 ---
    k_lin1<<<1024, 256, 0, stream>>>(x, W1, dinv, hs, n);
    k_gather<false><<<gRow, 256, 0, stream>>>(hs, offs, curs, perm, dinv, agg, n);

    // --- layer 2 (reuse hs for hs2; final dinv folded into gather) ---
    k_lin2<<<1024, 256, 0, stream>>>(agg, W2, dinv, hs, n);
    k_gather<true><<<gRow, 256, 0, stream>>>(hs, offs, curs, perm, dinv, out, n);
}

// Round 3
// 403.825 us; speedup vs baseline: 2.3442x; 1.4466x over previous
//
#include <hip/hip_runtime.h>
#include <hip/hip_bf16.h>

#define IN_DIM  128
#define OUT_DIM 64
#define SCAN_CHUNK 1024   // 256 threads x 4 elems

// ---------------------------------------------------------------------------
// CSR build: histogram -> exclusive scan -> scatter edges by dst
// ---------------------------------------------------------------------------
__global__ void k_zero(unsigned* __restrict__ p, int n) {
    int i = blockIdx.x * blockDim.x + threadIdx.x;
    if (i < n) p[i] = 0u;
}

__global__ void k_hist(const int* __restrict__ dst, unsigned* __restrict__ cnt, int nE) {
    int e = blockIdx.x * blockDim.x + threadIdx.x;
    if (e < nE) atomicAdd(&cnt[dst[e]], 1u);
}

// Per-block scan of 1024 counts; also emits dinv = rsqrt(deg) (deg = cnt+1 self-loop)
__global__ __launch_bounds__(256) void k_scanA(const unsigned* __restrict__ cnt,
                                               unsigned* __restrict__ offs,
                                               unsigned* __restrict__ partials,
                                               float* __restrict__ dinv, int n) {
    __shared__ unsigned sums[256];
    int base = blockIdx.x * SCAN_CHUNK + threadIdx.x * 4;
    unsigned v[4]; unsigned s = 0;
#pragma unroll
    for (int k = 0; k < 4; ++k) {
        int i = base + k;
        unsigned c = (i < n) ? cnt[i] : 0u;
        if (i < n) dinv[i] = rsqrtf((float)c + 1.0f);
        v[k] = s; s += c;
    }
    sums[threadIdx.x] = s;
    __syncthreads();
    for (int d = 1; d < 256; d <<= 1) {
        unsigned t = (threadIdx.x >= (unsigned)d) ? sums[threadIdx.x - d] : 0u;
        __syncthreads();
        sums[threadIdx.x] += t;
        __syncthreads();
    }
    unsigned excl = sums[threadIdx.x] - s;
#pragma unroll
    for (int k = 0; k < 4; ++k) {
        int i = base + k;
        if (i < n) offs[i] = excl + v[k];
    }
    if (threadIdx.x == 255) partials[blockIdx.x] = sums[255];
}

__global__ void k_scanB(unsigned* __restrict__ partials, int nb) {
    __shared__ unsigned s[256];
    unsigned v = (threadIdx.x < (unsigned)nb) ? partials[threadIdx.x] : 0u;
    s[threadIdx.x] = v;
    __syncthreads();
    for (int d = 1; d < 256; d <<= 1) {
        unsigned t = (threadIdx.x >= (unsigned)d) ? s[threadIdx.x - d] : 0u;
        __syncthreads();
        s[threadIdx.x] += t;
        __syncthreads();
    }
    if (threadIdx.x < (unsigned)nb) partials[threadIdx.x] = s[threadIdx.x] - v;
}

__global__ void k_scanC(unsigned* __restrict__ offs, const unsigned* __restrict__ partials,
                        unsigned* __restrict__ curs, int n) {
    int i = blockIdx.x * blockDim.x + threadIdx.x;
    if (i < n) {
        unsigned o = offs[i] + partials[i / SCAN_CHUNK];
        offs[i] = o;
        curs[i] = o;
    }
}

// ---------------------------------------------------------------------------
// 8-rows-per-wave linear tile: out[row] = dinv[row] * (f(in[row]) @ W)
// f = relu(dinv[row] * .) when RELU (layer-2 input), identity otherwise.
// W staged in LDS [k][64]; one W read amortized over 8 FMAs.
// ---------------------------------------------------------------------------
template <int KD, bool RELU>
__device__ __forceinline__ void lin_tile(const float* __restrict__ in,
                                         const float* __restrict__ Wl,
                                         const float* __restrict__ dinv,
                                         float* __restrict__ outp,
                                         int n, int tile, int wid, int lane) {
    int r0 = (tile * 4 + wid) * 8;
    if (r0 >= n) return;
    const float4* base[8];
    float dv[8];
    int rows[8];
#pragma unroll
    for (int r = 0; r < 8; ++r) {
        int row = r0 + r; if (row > n - 1) row = n - 1;   // dup-tail benign
        rows[r] = row;
        base[r] = (const float4*)(in + (size_t)row * KD);
        dv[r] = dinv[row];
    }
    float acc[8] = {0.f, 0.f, 0.f, 0.f, 0.f, 0.f, 0.f, 0.f};
    for (int k4 = 0; k4 < KD / 4; ++k4) {
        float w0 = Wl[(4 * k4 + 0) * 64 + lane];
        float w1 = Wl[(4 * k4 + 1) * 64 + lane];
        float w2 = Wl[(4 * k4 + 2) * 64 + lane];
        float w3 = Wl[(4 * k4 + 3) * 64 + lane];
#pragma unroll
        for (int r = 0; r < 8; ++r) {
            float4 xv = base[r][k4];                 // wave-uniform broadcast
            float a = xv.x, b = xv.y, c = xv.z, d = xv.w;
            if (RELU) {
                a = fmaxf(dv[r] * a, 0.f); b = fmaxf(dv[r] * b, 0.f);
                c = fmaxf(dv[r] * c, 0.f); d = fmaxf(dv[r] * d, 0.f);
            }
            acc[r] += a * w0 + b * w1 + c * w2 + d * w3;
        }
    }
#pragma unroll
    for (int r = 0; r < 8; ++r)
        outp[(size_t)rows[r] * 64 + lane] = dv[r] * acc[r];
}

// ---------------------------------------------------------------------------
// Mega kernel: interleaved {layer-1 linear tiles} + {CSR edge scatter}.
// Lin work (VALU/LDS-bound) hides inside scatter's memory stalls.
// ---------------------------------------------------------------------------
__global__ __launch_bounds__(256) void k_mega(const float* __restrict__ x,
                                              const float* __restrict__ W,
                                              const float* __restrict__ dinv,
                                              float* __restrict__ hs, int n,
                                              const int* __restrict__ src,
                                              const int* __restrict__ dst,
                                              unsigned* __restrict__ curs,
                                              int* __restrict__ perm, int nE) {
    int nL = (n + 31) / 32;            // 32 rows per lin block
    int nS = (nE + 255) / 256;         // 256 edges per scatter block
    long tot = nL + nS;
    long b = blockIdx.x;
    int lo = (int)((b * nL) / tot);
    int hi = (int)(((b + 1) * nL) / tot);
    if (hi > lo) {
        // ---- lin1 tile ----
        __shared__ float Wl[IN_DIM * OUT_DIM];   // 32 KiB
        for (int i = threadIdx.x; i < IN_DIM * OUT_DIM; i += 256) Wl[i] = W[i];
        __syncthreads();
        lin_tile<IN_DIM, false>(x, Wl, dinv, hs, n, lo,
                                threadIdx.x >> 6, threadIdx.x & 63);
    } else {
        // ---- scatter chunk ----
        int sIdx = (int)(b - lo);
        int e = sIdx * 256 + threadIdx.x;
        if (e < nE) {
            unsigned p = atomicAdd(&curs[dst[e]], 1u);
            perm[p] = src[e];
        }
    }
}

// Standalone layer-2 linear (relu fused on input)
__global__ __launch_bounds__(256) void k_lin2(const float* __restrict__ agg1,
                                              const float* __restrict__ W,
                                              const float* __restrict__ dinv,
                                              float* __restrict__ hs2, int n) {
    __shared__ float Wl[OUT_DIM * OUT_DIM];  // 16 KiB
    for (int i = threadIdx.x; i < OUT_DIM * OUT_DIM; i += 256) Wl[i] = W[i];
    __syncthreads();
    lin_tile<OUT_DIM, true>(agg1, Wl, dinv, hs2, n, blockIdx.x,
                            threadIdx.x >> 6, threadIdx.x & 63);
}

// ---------------------------------------------------------------------------
// CSR gather, 4-way ILP: one wave per node, lane = feature dim.
// ---------------------------------------------------------------------------
template <bool FIN>
__global__ __launch_bounds__(256) void k_gather(const float* __restrict__ hs,
                                                const unsigned* __restrict__ offs,
                                                const unsigned* __restrict__ ends,
                                                const int* __restrict__ perm,
                                                const float* __restrict__ dinv,
                                                float* __restrict__ outb, int n) {
    int lane = threadIdx.x & 63;
    int r = blockIdx.x * 4 + (threadIdx.x >> 6);
    if (r >= n) return;
    unsigned beg = offs[r], end = ends[r];
    float a0 = hs[(size_t)r * 64 + lane];            // self-loop term
    float a1 = 0.f, a2 = 0.f, a3 = 0.f;
    for (unsigned e0 = beg; e0 < end; e0 += 64) {
        unsigned c = min(64u, end - e0);
        int sl = (lane < (int)c) ? perm[e0 + lane] : 0;
        unsigned k = 0;
        for (; k + 4 <= c; k += 4) {
            int s0 = __shfl(sl, (int)k);
            int s1 = __shfl(sl, (int)k + 1);
            int s2 = __shfl(sl, (int)k + 2);
            int s3 = __shfl(sl, (int)k + 3);
            float v0 = hs[(size_t)s0 * 64 + lane];
            float v1 = hs[(size_t)s1 * 64 + lane];
            float v2 = hs[(size_t)s2 * 64 + lane];
            float v3 = hs[(size_t)s3 * 64 + lane];
            a0 += v0; a1 += v1; a2 += v2; a3 += v3;
        }
        for (; k < c; ++k) {
            int s = __shfl(sl, (int)k);
            a0 += hs[(size_t)s * 64 + lane];
        }
    }
    float acc = (a0 + a1) + (a2 + a3);
    if (FIN) acc *= dinv[r];
    outb[(size_t)r * 64 + lane] = acc;
}

// ---------------------------------------------------------------------------
extern "C" void kernel_launch(void* const* d_in, const int* in_sizes, int n_in,
                              void* d_out, int out_size, void* d_ws, size_t ws_size,
                              hipStream_t stream) {
    const float* x  = (const float*)d_in[0];
    const int*   ei = (const int*)d_in[1];
    const float* W1 = (const float*)d_in[2];
    const float* W2 = (const float*)d_in[3];
    float* out = (float*)d_out;

    int n  = in_sizes[0] / IN_DIM;   // 100000
    int nE = in_sizes[1] / 2;        // 1600000
    const int* src = ei;
    const int* dst = ei + nE;

    char* w = (char*)d_ws;
    size_t nAl = ((size_t)n * 4 + 255) & ~(size_t)255;
    float*    dinv     = (float*)w;                 w += nAl;
    unsigned* cnt      = (unsigned*)w;              w += nAl;
    unsigned* offs     = (unsigned*)w;              w += nAl;
    unsigned* curs     = (unsigned*)w;              w += nAl;
    unsigned* partials = (unsigned*)w;              w += 4096;
    int*      perm     = (int*)w;                   w += ((size_t)nE * 4 + 255) & ~(size_t)255;
    float*    hs       = (float*)w;                 w += (size_t)n * 64 * 4;
    float*    agg      = (float*)w;

    int nb   = (n + SCAN_CHUNK - 1) / SCAN_CHUNK;
    int gE   = (nE + 255) / 256;
    int gN   = (n + 255) / 256;
    int gRow = (n + 3) / 4;
    int nL   = (n + 31) / 32;
    int nS   = (nE + 255) / 256;

    // --- CSR build prologue ---
    k_zero<<<gN, 256, 0, stream>>>(cnt, n);
    k_hist<<<gE, 256, 0, stream>>>(dst, cnt, nE);
    k_scanA<<<nb, 256, 0, stream>>>(cnt, offs, partials, dinv, n);
    k_scanB<<<1, 256, 0, stream>>>(partials, nb);
    k_scanC<<<gN, 256, 0, stream>>>(offs, partials, curs, n);

    // --- fused: layer-1 linear + edge scatter ---
    k_mega<<<nL + nS, 256, 0, stream>>>(x, W1, dinv, hs, n, src, dst, curs, perm, nE);
    // after mega: curs[r] == row end

    // --- layer 1 aggregate ---
    k_gather<false><<<gRow, 256, 0, stream>>>(hs, offs, curs, perm, dinv, agg, n);

    // --- layer 2 ---
    k_lin2<<<nL, 256, 0, stream>>>(agg, W2, dinv, hs, n);
    k_gather<true><<<gRow, 256, 0, stream>>>(hs, offs, curs, perm, dinv, out, n);
}